// Round 2
// baseline (23336.006 us; speedup 1.0000x reference)
//
#include <hip/hip_runtime.h>
#include <math.h>

#pragma clang fp contract(off)

#define BB 64      // batch
#define N_IN 64
#define N_E 256
#define N_I 64
#define N_OUT 10

// Single wave per batch. All spike masks are wave-uniform 64-bit ballots held
// in SGPRs; no __syncthreads in the time loop, no LDS mask round-trips.
// Lane l owns E neurons {l, l+64, l+128, l+192}, I neuron l, output l (l<10).
// All gather sums are in ascending presynaptic index order, matching the
// round-1 kernel that was bit-exact (absmax 0.0) vs the numpy reference.
__global__ __launch_bounds__(64) void ping_kernel(
    const float* __restrict__ g_in,   // [T,64,64]
    const float* __restrict__ g_W0,   // [64,256]  clamp >=0 at use
    const float* __restrict__ g_W1,   // [256,10]  clamp >=0 at stage
    const float* __restrict__ g_Wee,  // [256,256]
    const float* __restrict__ g_Wei,  // [256,64]
    const float* __restrict__ g_Wie,  // [64,256]
    float* __restrict__ g_out,        // [64,10]
    int T, float dA, float dG)
{
  const int lane = threadIdx.x;
  const int b    = blockIdx.x;
  const int col  = (lane < N_OUT) ? lane : 0;

  __shared__ float sh_W1[N_E * N_OUT];   // 10 KB, clamped
  for (int k = lane; k < N_E * N_OUT; k += 64) sh_W1[k] = fmaxf(g_W1[k], 0.f);

  // Detect all-zero W_ee (true for this data). Skipping a zero matmul is
  // fp-exact (x + 0.0f == x for the nonnegative sums here).
  bool any = false;
  {
    const float4* p = (const float4*)g_Wee;
    for (int k = lane; k < (N_E * N_E / 4); k += 64) {
      float4 x = p[k];
      any |= (x.x != 0.f) | (x.y != 0.f) | (x.z != 0.f) | (x.w != 0.f);
    }
  }
  const bool wee = (__ballot(any) != 0ull);
  __syncthreads();   // single-wave barrier: LDS staging visible

  // E state: slot s -> neuron lane + 64*s
  float vE[4]  = {-65.f, -65.f, -65.f, -65.f};
  float geA[4] = {0.f, 0.f, 0.f, 0.f};
  float giA[4] = {0.f, 0.f, 0.f, 0.f};
  int   rE[4]  = {0, 0, 0, 0};
  // I state (neuron = lane)
  float vI = -65.f, gI = 0.f; int rI = 0;
  // output state (lanes < 10)
  float vO = -65.f, gO = 0.f, accO = 0.f; int rO = 0;

  // spike masks (wave-uniform)
  unsigned long long mE[4] = {0ull, 0ull, 0ull, 0ull};
  unsigned long long mI = 0ull;

  float cur = g_in[b * N_IN + lane];   // t = 0 input row
  for (int t = 0; t < T; ++t) {
    const int tn = (t + 1 < T) ? (t + 1) : (T - 1);
    float nxt = g_in[(tn * BB + b) * N_IN + lane];   // prefetch next step

    const unsigned long long mIn = __ballot(cur != 0.f);

    // ---- fused gathers over PREVIOUS-step masks: input->E, I->E, E->I ----
    float kin[4] = {0.f, 0.f, 0.f, 0.f};   // s_in @ W0 (clamped), col = lane+64s
    float kie[4] = {0.f, 0.f, 0.f, 0.f};   // s_i @ W_ie, col = lane+64s
    float p0 = 0.f, p1 = 0.f, p2 = 0.f, p3 = 0.f;  // s_e @ W_ei word-partials, col = lane
    {
      unsigned long long a = mIn, c = mI;
      unsigned long long e0 = mE[0], e1 = mE[1], e2 = mE[2], e3 = mE[3];
      while (a | c | e0 | e1 | e2 | e3) {
        bool va[2]; int ja[2];
#pragma unroll
        for (int k = 0; k < 2; ++k) {
          va[k] = (a != 0ull); ja[k] = va[k] ? (__ffsll((unsigned long long)a) - 1) : 0;
          a &= (a - 1ull);
        }
        bool vc[2]; int jc[2];
#pragma unroll
        for (int k = 0; k < 2; ++k) {
          vc[k] = (c != 0ull); jc[k] = vc[k] ? (__ffsll((unsigned long long)c) - 1) : 0;
          c &= (c - 1ull);
        }
        bool v0[4]; int j0[4];
#pragma unroll
        for (int k = 0; k < 4; ++k) {
          v0[k] = (e0 != 0ull); j0[k] = v0[k] ? (__ffsll((unsigned long long)e0) - 1) : 0;
          e0 &= (e0 - 1ull);
        }
        bool v1[4]; int j1[4];
#pragma unroll
        for (int k = 0; k < 4; ++k) {
          v1[k] = (e1 != 0ull); j1[k] = v1[k] ? (__ffsll((unsigned long long)e1) - 1) : 0;
          e1 &= (e1 - 1ull);
        }
        bool v2[4]; int j2[4];
#pragma unroll
        for (int k = 0; k < 4; ++k) {
          v2[k] = (e2 != 0ull); j2[k] = v2[k] ? (__ffsll((unsigned long long)e2) - 1) : 0;
          e2 &= (e2 - 1ull);
        }
        bool v3[4]; int j3[4];
#pragma unroll
        for (int k = 0; k < 4; ++k) {
          v3[k] = (e3 != 0ull); j3[k] = v3[k] ? (__ffsll((unsigned long long)e3) - 1) : 0;
          e3 &= (e3 - 1ull);
        }
        // issue all loads together (up to 24 in flight -> one latency round)
        float fa[2][4], fc[2][4];
#pragma unroll
        for (int k = 0; k < 2; ++k)
#pragma unroll
          for (int s = 0; s < 4; ++s) {
            fa[k][s] = fmaxf(g_W0[ja[k] * N_E + lane + 64 * s], 0.f);
            fc[k][s] = g_Wie[jc[k] * N_E + lane + 64 * s];
          }
        float f0[4], f1[4], f2[4], f3[4];
#pragma unroll
        for (int k = 0; k < 4; ++k) {
          f0[k] = g_Wei[(j0[k]) * N_I + lane];
          f1[k] = g_Wei[(64 + j1[k]) * N_I + lane];
          f2[k] = g_Wei[(128 + j2[k]) * N_I + lane];
          f3[k] = g_Wei[(192 + j3[k]) * N_I + lane];
        }
        // accumulate (ascending order preserved per accumulator)
#pragma unroll
        for (int k = 0; k < 2; ++k) {
#pragma unroll
          for (int s = 0; s < 4; ++s) {
            kin[s] += va[k] ? fa[k][s] : 0.f;
            kie[s] += vc[k] ? fc[k][s] : 0.f;
          }
        }
#pragma unroll
        for (int k = 0; k < 4; ++k) {
          p0 += v0[k] ? f0[k] : 0.f;
          p1 += v1[k] ? f1[k] : 0.f;
          p2 += v2[k] ? f2[k] : 0.f;
          p3 += v3[k] ? f3[k] : 0.f;
        }
      }
    }

    // ---- E<-E recurrent (skipped when W_ee == 0; full-ascending if not) ----
    float keA[4] = {0.f, 0.f, 0.f, 0.f};
    if (wee) {
      unsigned long long m0 = mE[0], m1 = mE[1], m2 = mE[2], m3 = mE[3];
      while (m0 | m1 | m2 | m3) {
        bool v[4]; int j[4];
#pragma unroll
        for (int k = 0; k < 4; ++k) {
          bool h0 = (m0 != 0ull), h1 = (m1 != 0ull), h2 = (m2 != 0ull), h3 = (m3 != 0ull);
          int idx = 0;
          if (h0)      { idx = __ffsll((unsigned long long)m0) - 1;       m0 &= (m0 - 1ull); }
          else if (h1) { idx = 64 + __ffsll((unsigned long long)m1) - 1;  m1 &= (m1 - 1ull); }
          else if (h2) { idx = 128 + __ffsll((unsigned long long)m2) - 1; m2 &= (m2 - 1ull); }
          else if (h3) { idx = 192 + __ffsll((unsigned long long)m3) - 1; m3 &= (m3 - 1ull); }
          v[k] = h0 | h1 | h2 | h3; j[k] = idx;
        }
        float f[4][4];
#pragma unroll
        for (int k = 0; k < 4; ++k)
#pragma unroll
          for (int s = 0; s < 4; ++s) f[k][s] = g_Wee[j[k] * N_E + lane + 64 * s];
#pragma unroll
        for (int k = 0; k < 4; ++k)
#pragma unroll
          for (int s = 0; s < 4; ++s) keA[s] += v[k] ? f[k][s] : 0.f;
      }
    }

    // ---- E LIF (COBA, C_m=1, g_L=0.05, ref=12) + fresh E ballots ----
    unsigned long long nE[4];
#pragma unroll
    for (int s = 0; s < 4; ++s) {
      geA[s] = ((geA[s] + kin[s]) + keA[s]) * dA;
      giA[s] = (giA[s] + kie[s]) * dG;
      float t2 = geA[s] * (0.f - vE[s]);
      float t3 = giA[s] * (-80.f - vE[s]);
      float Itot = t2 + t3;
      float dv = 0.25f * ((-0.05f) * (vE[s] - (-65.f)) + Itot);
      dv = dv * 0.0125f + dv * 0.9875f;        // _scale_grad forward (not fp-identity)
      vE[s] = fmaxf(vE[s] + dv, -200.f);
      rE[s] = rE[s] - 1; if (rE[s] < 0) rE[s] = 0;
      bool can = (rE[s] == 0);
      bool sE = ((vE[s] - (-50.f)) >= 0.f) && can;
      vE[s] = (sE || !can) ? -65.f : vE[s];
      rE[s] = sE ? 12 : rE[s];
      nE[s] = __ballot(sE);
    }

    // ---- output gather over FRESH E spikes from LDS W1 (full-ascending) ----
    float ko = 0.f;
    {
      unsigned long long m0 = nE[0], m1 = nE[1], m2 = nE[2], m3 = nE[3];
      while (m0 | m1 | m2 | m3) {
        bool v[8]; int j[8];
#pragma unroll
        for (int k = 0; k < 8; ++k) {
          bool h0 = (m0 != 0ull), h1 = (m1 != 0ull), h2 = (m2 != 0ull), h3 = (m3 != 0ull);
          int idx = 0;
          if (h0)      { idx = __ffsll((unsigned long long)m0) - 1;       m0 &= (m0 - 1ull); }
          else if (h1) { idx = 64 + __ffsll((unsigned long long)m1) - 1;  m1 &= (m1 - 1ull); }
          else if (h2) { idx = 128 + __ffsll((unsigned long long)m2) - 1; m2 &= (m2 - 1ull); }
          else if (h3) { idx = 192 + __ffsll((unsigned long long)m3) - 1; m3 &= (m3 - 1ull); }
          v[k] = h0 | h1 | h2 | h3; j[k] = idx;
        }
        float f[8];
#pragma unroll
        for (int k = 0; k < 8; ++k) f[k] = sh_W1[j[k] * N_OUT + col];
#pragma unroll
        for (int k = 0; k < 8; ++k) ko += v[k] ? f[k] : 0.f;
      }
    }

    // ---- I LIF (C_m=0.5, g_L=0.1, ref=6); E->I sum = ((p0+p1)+p2)+p3 ----
    {
      float p = ((p0 + p1) + p2) + p3;
      gI = (gI + p) * dA;
      float Ii = gI * (0.f - vI);
      float dvi = 0.5f * ((-0.1f) * (vI - (-65.f)) + Ii);
      dvi = dvi * 0.0125f + dvi * 0.9875f;
      vI = fmaxf(vI + dvi, -200.f);
      rI = rI - 1; if (rI < 0) rI = 0;
      bool canI = (rI == 0);
      bool sI = ((vI - (-50.f)) >= 0.f) && canI;
      vI = (sI || !canI) ? -65.f : vI;
      rI = sI ? 6 : rI;
      mI = __ballot(sI);
    }

    // ---- output LIF (C_m=1, g_L=0.05, ref=12) ----
    if (lane < N_OUT) {
      gO = (gO + ko) * dA;
      float Io = gO * (0.f - vO);
      float dvo = 0.25f * ((-0.05f) * (vO - (-65.f)) + Io);
      dvo = dvo * 0.0125f + dvo * 0.9875f;
      vO = fmaxf(vO + dvo, -200.f);
      rO = rO - 1; if (rO < 0) rO = 0;
      bool canO = (rO == 0);
      bool sO = ((vO - (-50.f)) >= 0.f) && canO;
      vO = (sO || !canO) ? -65.f : vO;
      rO = sO ? 12 : rO;
      accO += sO ? 1.f : 0.f;
    }

    mE[0] = nE[0]; mE[1] = nE[1]; mE[2] = nE[2]; mE[3] = nE[3];
    cur = nxt;
  }

  if (lane < N_OUT) g_out[b * N_OUT + lane] = accO;
}

extern "C" void kernel_launch(void* const* d_in, const int* in_sizes, int n_in,
                              void* d_out, int out_size, void* d_ws, size_t ws_size,
                              hipStream_t stream) {
  const float* g_in  = (const float*)d_in[0];
  const float* g_W0  = (const float*)d_in[1];
  const float* g_W1  = (const float*)d_in[2];
  const float* g_Wee = (const float*)d_in[3];
  const float* g_Wei = (const float*)d_in[4];
  const float* g_Wie = (const float*)d_in[5];
  float* out = (float*)d_out;
  int T = in_sizes[0] / (BB * N_IN);
  float dA = (float)exp(-0.25 / 2.0);   // tau_ampa = 2.0
  float dG = (float)exp(-0.25 / 9.0);   // tau_gaba = 9.0
  ping_kernel<<<dim3(BB), dim3(64), 0, stream>>>(g_in, g_W0, g_W1, g_Wee, g_Wei, g_Wie, out, T, dA, dG);
}

// Round 3
// 6456.297 us; speedup vs baseline: 3.6145x; 3.6145x over previous
//
#include <hip/hip_runtime.h>
#include <math.h>

#pragma clang fp contract(off)

#define BB 64      // batch
#define N_IN 64
#define N_E 256
#define N_I 64
#define N_OUT 10

// One block (256 thr = 4 waves) per batch. Wave w owns E neurons [w*64, w*64+64).
// All spike masks are in-register wave-uniform ballots:
//   - each wave's E-word mask is its own ballot (prev step, SGPR)
//   - the I mask is computed REDUNDANTLY by all 4 waves (identical fp ops ->
//     identical ballot), so it is also in-register everywhere.
// Only fp32 partial sums (E->I per-word, E->O per-word) cross waves, via
// double-buffered LDS -> exactly ONE __syncthreads per time step.
// Wie/Wei/W1 staged in LDS (~141 KB); W0 gather stays global (input spikes are
// ~1.3/step) and overlaps LDS reads (vmcnt vs lgkmcnt).
// Summation orders match the bit-exact round-1/2 kernels (ascending within
// word, word partials combined ((p0+p1)+p2)+p3).
__global__ __launch_bounds__(256) void ping_kernel(
    const float* __restrict__ g_in,   // [T,64,64]
    const float* __restrict__ g_W0,   // [64,256]  clamp >=0 at use
    const float* __restrict__ g_W1,   // [256,10]  clamp >=0 at stage
    const float* __restrict__ g_Wee,  // [256,256]
    const float* __restrict__ g_Wei,  // [256,64]
    const float* __restrict__ g_Wie,  // [64,256]
    float* __restrict__ g_out,        // [64,10]
    int T, float dA, float dG)
{
  const int tid  = threadIdx.x;
  const int lane = tid & 63;
  const int wav  = tid >> 6;
  const int b    = blockIdx.x;
  const int col  = (lane < N_OUT) ? lane : 0;

  __shared__ float sWie[N_I * N_E];          // 64 KB  I->E rows
  __shared__ float sWei[N_E * N_I];          // 64 KB  E->I rows
  __shared__ float sW1[N_E * N_OUT];         // 10 KB  E->O rows (clamped)
  __shared__ float sP[2][4][64];             // E->I word partials (dbuf)
  __shared__ float sKo[2][4][16];            // E->O word partials (dbuf)
  __shared__ unsigned long long sME[2][4];   // E masks (only for wee fallback)
  __shared__ int sWee;

  // ---- one-time staging ----
  {
    const float4* s0 = (const float4*)g_Wie; float4* d0 = (float4*)sWie;
    for (int k = tid; k < (N_I * N_E) / 4; k += 256) d0[k] = s0[k];
    const float4* s1 = (const float4*)g_Wei; float4* d1 = (float4*)sWei;
    for (int k = tid; k < (N_E * N_I) / 4; k += 256) d1[k] = s1[k];
    for (int k = tid; k < N_E * N_OUT; k += 256) sW1[k] = fmaxf(g_W1[k], 0.f);
  }
  if (tid < 4) { sME[0][tid] = 0ull; sME[1][tid] = 0ull; }
  if (tid == 0) sWee = 0;
  // detect all-zero W_ee (true for this data; skipping a zero matmul is fp-exact)
  {
    bool any = false;
    const float4* p = (const float4*)g_Wee;
    for (int k = tid; k < (N_E * N_E) / 4; k += 256) {
      float4 x = p[k];
      any |= (x.x != 0.f) | (x.y != 0.f) | (x.z != 0.f) | (x.w != 0.f);
    }
    if (__ballot(any) != 0ull && lane == 0) sWee = 1;
  }
  __syncthreads();
  const int wee = sWee;

  // ---- per-thread state ----
  float vE = -65.f, ge = 0.f, gi = 0.f; int rE = 0;   // E neuron = tid
  float vI = -65.f, gI = 0.f; int rI = 0;             // I neuron = lane (replicated/wave)
  float vO = -65.f, gO = 0.f, accO = 0.f; int rO = 0; // output (wave 0, lanes<10)

  unsigned long long mE = 0ull;   // prev-step E mask, own word (SGPR)
  unsigned long long mI = 0ull;   // prev-step I mask (SGPR, replicated)

  int par = 0;
  float cur = g_in[b * N_IN + lane];   // t=0 input row (redundant per wave)
  for (int t = 0; t < T; ++t) {
    const int tn = (t + 1 < T) ? (t + 1) : (T - 1);
    float nxt = g_in[(tn * BB + b) * N_IN + lane];   // prefetch next step

    const unsigned long long mIn = __ballot(cur != 0.f);

    // ---- phase A: fused gathers over PREVIOUS masks ----
    // kin: s_in @ W0 (global, clamped), col=tid
    // kie: s_i  @ W_ie (LDS), col=tid
    // pEI: word-w partial of s_e @ W_ei (LDS), col=lane
    float kin = 0.f, kie = 0.f, pEI = 0.f;
    {
      unsigned long long a = mIn, c = mI, e = mE;
      while (a | c | e) {
        int ja[4]; bool va[4];
#pragma unroll
        for (int k = 0; k < 4; ++k) {
          va[k] = (a != 0ull); ja[k] = va[k] ? (__ffsll(a) - 1) : 0; a &= (a - 1ull);
        }
        int jc[8]; bool vc[8];
#pragma unroll
        for (int k = 0; k < 8; ++k) {
          vc[k] = (c != 0ull); jc[k] = vc[k] ? (__ffsll(c) - 1) : 0; c &= (c - 1ull);
        }
        int je[8]; bool ve[8];
#pragma unroll
        for (int k = 0; k < 8; ++k) {
          ve[k] = (e != 0ull); je[k] = ve[k] ? (__ffsll(e) - 1) : 0; e &= (e - 1ull);
        }
        float fa[4];
#pragma unroll
        for (int k = 0; k < 4; ++k) fa[k] = fmaxf(g_W0[ja[k] * N_E + tid], 0.f);
        float fc[8], fe[8];
#pragma unroll
        for (int k = 0; k < 8; ++k) {
          fc[k] = sWie[jc[k] * N_E + tid];
          fe[k] = sWei[(wav * 64 + je[k]) * N_I + lane];
        }
#pragma unroll
        for (int k = 0; k < 4; ++k) kin += va[k] ? fa[k] : 0.f;
#pragma unroll
        for (int k = 0; k < 8; ++k) kie += vc[k] ? fc[k] : 0.f;
#pragma unroll
        for (int k = 0; k < 8; ++k) pEI += ve[k] ? fe[k] : 0.f;
      }
    }

    // ---- E<-E recurrent fallback (dead for this data) ----
    float kee = 0.f;
    if (wee) {
      unsigned long long m0 = sME[par][0], m1 = sME[par][1];
      unsigned long long m2 = sME[par][2], m3 = sME[par][3];
      while (m0 | m1 | m2 | m3) {
        bool v[4]; int j[4];
#pragma unroll
        for (int k = 0; k < 4; ++k) {
          bool h0 = (m0 != 0ull), h1 = (m1 != 0ull), h2 = (m2 != 0ull), h3 = (m3 != 0ull);
          int idx = 0;
          if (h0)      { idx = __ffsll(m0) - 1;       m0 &= (m0 - 1ull); }
          else if (h1) { idx = 64 + __ffsll(m1) - 1;  m1 &= (m1 - 1ull); }
          else if (h2) { idx = 128 + __ffsll(m2) - 1; m2 &= (m2 - 1ull); }
          else if (h3) { idx = 192 + __ffsll(m3) - 1; m3 &= (m3 - 1ull); }
          v[k] = h0 | h1 | h2 | h3; j[k] = idx;
        }
        float f[4];
#pragma unroll
        for (int k = 0; k < 4; ++k) f[k] = g_Wee[j[k] * N_E + tid];
#pragma unroll
        for (int k = 0; k < 4; ++k) kee += v[k] ? f[k] : 0.f;
      }
    }

    // ---- E LIF (COBA, C_m=1, g_L=0.05, ref=12) ----
    ge = ((ge + kin) + kee) * dA;
    gi = (gi + kie) * dG;
    {
      float t2 = ge * (0.f - vE);
      float t3 = gi * (-80.f - vE);
      float Itot = t2 + t3;
      float dv = 0.25f * ((-0.05f) * (vE - (-65.f)) + Itot);
      dv = dv * 0.0125f + dv * 0.9875f;      // _scale_grad forward (not fp-identity)
      vE = fmaxf(vE + dv, -200.f);
      rE = rE - 1; if (rE < 0) rE = 0;
      bool can = (rE == 0);
      bool sE = ((vE - (-50.f)) >= 0.f) && can;
      vE = (sE || !can) ? -65.f : vE;
      rE = sE ? 12 : rE;
      unsigned long long fresh = __ballot(sE);
      if (lane == 0) sME[par ^ 1][wav] = fresh;   // only needed by wee path

      // ---- E->O word partial over FRESH own-word mask (LDS W1) ----
      float ko = 0.f;
      {
        unsigned long long m = fresh;
        while (m) {
          int j[8]; bool v[8];
#pragma unroll
          for (int k = 0; k < 8; ++k) {
            v[k] = (m != 0ull); j[k] = v[k] ? (__ffsll(m) - 1) : 0; m &= (m - 1ull);
          }
          float f[8];
#pragma unroll
          for (int k = 0; k < 8; ++k) f[k] = sW1[(wav * 64 + j[k]) * N_OUT + col];
#pragma unroll
          for (int k = 0; k < 8; ++k) ko += v[k] ? f[k] : 0.f;
        }
      }
      sP[par][wav][lane] = pEI;
      if (lane < N_OUT) sKo[par][wav][lane] = ko;
      mE = fresh;
    }

    __syncthreads();   // the ONLY barrier per step: partials visible

    // ---- phase B: I LIF replicated on every wave (identical -> same ballot) ----
    {
      float p = ((sP[par][0][lane] + sP[par][1][lane]) + sP[par][2][lane]) + sP[par][3][lane];
      gI = (gI + p) * dA;
      float Ii = gI * (0.f - vI);
      float dvi = 0.5f * ((-0.1f) * (vI - (-65.f)) + Ii);
      dvi = dvi * 0.0125f + dvi * 0.9875f;
      vI = fmaxf(vI + dvi, -200.f);
      rI = rI - 1; if (rI < 0) rI = 0;
      bool canI = (rI == 0);
      bool sI = ((vI - (-50.f)) >= 0.f) && canI;
      vI = (sI || !canI) ? -65.f : vI;
      rI = sI ? 6 : rI;
      mI = __ballot(sI);
    }

    // ---- output LIF (wave 0 only; reads step-t sKo before its next barrier,
    //      other waves race ahead writing buffer par^1 — safe) ----
    if (wav == 0 && lane < N_OUT) {
      float k4 = ((sKo[par][0][lane] + sKo[par][1][lane]) + sKo[par][2][lane]) + sKo[par][3][lane];
      gO = (gO + k4) * dA;
      float Io = gO * (0.f - vO);
      float dvo = 0.25f * ((-0.05f) * (vO - (-65.f)) + Io);
      dvo = dvo * 0.0125f + dvo * 0.9875f;
      vO = fmaxf(vO + dvo, -200.f);
      rO = rO - 1; if (rO < 0) rO = 0;
      bool canO = (rO == 0);
      bool sO = ((vO - (-50.f)) >= 0.f) && canO;
      vO = (sO || !canO) ? -65.f : vO;
      rO = sO ? 12 : rO;
      accO += sO ? 1.f : 0.f;
    }

    par ^= 1;
    cur = nxt;
  }

  if (wav == 0 && lane < N_OUT) g_out[b * N_OUT + lane] = accO;
}

extern "C" void kernel_launch(void* const* d_in, const int* in_sizes, int n_in,
                              void* d_out, int out_size, void* d_ws, size_t ws_size,
                              hipStream_t stream) {
  const float* g_in  = (const float*)d_in[0];
  const float* g_W0  = (const float*)d_in[1];
  const float* g_W1  = (const float*)d_in[2];
  const float* g_Wee = (const float*)d_in[3];
  const float* g_Wei = (const float*)d_in[4];
  const float* g_Wie = (const float*)d_in[5];
  float* out = (float*)d_out;
  int T = in_sizes[0] / (BB * N_IN);
  float dA = (float)exp(-0.25 / 2.0);   // tau_ampa = 2.0
  float dG = (float)exp(-0.25 / 9.0);   // tau_gaba = 9.0
  ping_kernel<<<dim3(BB), dim3(256), 0, stream>>>(g_in, g_W0, g_W1, g_Wee, g_Wei, g_Wie, out, T, dA, dG);
}

// Round 4
// 6098.432 us; speedup vs baseline: 3.8266x; 1.0587x over previous
//
#include <hip/hip_runtime.h>
#include <math.h>

#pragma clang fp contract(off)

#define BB 64      // batch
#define N_IN 64
#define N_E 256
#define N_I 64
#define N_OUT 10

// Raw workgroup barrier: drains ONLY lgkmcnt (LDS) — pending global loads
// (vmcnt) stay in flight across it, unlike __syncthreads which emits
// s_waitcnt vmcnt(0) and pulls HBM prefetch latency into the critical path.
// Cross-wave communication here is exclusively LDS, so lgkmcnt(0) suffices.
__device__ inline void wg_barrier_lds() {
  asm volatile("s_waitcnt lgkmcnt(0)\n\ts_barrier" ::: "memory");
}

// One block (256 thr = 4 waves) per batch. Wave w owns E word w (E neuron = tid).
// Masks: own E word + replicated-I ballot live in SGPRs; only fp32 partial sums
// cross waves via double-buffered LDS -> ONE light barrier per step.
// Wie/Wei/W1 staged in LDS (~141 KB). W0 gather: loads issued before the LDS
// gather loop, consumed after (vmcnt wait overlaps LDS work). Input prefetched
// TWO steps ahead (2-step slack > HBM latency, survives the raw barrier).
// Summation orders identical to the bit-exact round-3 kernel.
__global__ __launch_bounds__(256) void ping_kernel(
    const float* __restrict__ g_in,   // [T,64,64]
    const float* __restrict__ g_W0,   // [64,256]  clamp >=0 at use
    const float* __restrict__ g_W1,   // [256,10]  clamp >=0 at stage
    const float* __restrict__ g_Wee,  // [256,256]
    const float* __restrict__ g_Wei,  // [256,64]
    const float* __restrict__ g_Wie,  // [64,256]
    float* __restrict__ g_out,        // [64,10]
    int T, float dA, float dG)
{
  const int tid  = threadIdx.x;
  const int lane = tid & 63;
  const int wav  = tid >> 6;
  const int b    = blockIdx.x;
  const int col  = (lane < N_OUT) ? lane : 0;

  __shared__ float sWie[N_I * N_E];          // 64 KB  I->E rows
  __shared__ float sWei[N_E * N_I];          // 64 KB  E->I rows
  __shared__ float sW1[N_E * N_OUT];         // 10 KB  E->O rows (clamped)
  __shared__ float sP[2][4][64];             // E->I word partials (dbuf)
  __shared__ float sKo[2][4][16];            // E->O word partials (dbuf)
  __shared__ unsigned long long sME[2][4];   // E masks (wee fallback only)
  __shared__ int sWee;

  // ---- one-time staging ----
  {
    const float4* s0 = (const float4*)g_Wie; float4* d0 = (float4*)sWie;
    for (int k = tid; k < (N_I * N_E) / 4; k += 256) d0[k] = s0[k];
    const float4* s1 = (const float4*)g_Wei; float4* d1 = (float4*)sWei;
    for (int k = tid; k < (N_E * N_I) / 4; k += 256) d1[k] = s1[k];
    for (int k = tid; k < N_E * N_OUT; k += 256) sW1[k] = fmaxf(g_W1[k], 0.f);
  }
  if (tid < 4) { sME[0][tid] = 0ull; sME[1][tid] = 0ull; }
  if (tid == 0) sWee = 0;
  // detect all-zero W_ee (true for this data; skipping a zero matmul is fp-exact)
  {
    bool any = false;
    const float4* p = (const float4*)g_Wee;
    for (int k = tid; k < (N_E * N_E) / 4; k += 256) {
      float4 x = p[k];
      any |= (x.x != 0.f) | (x.y != 0.f) | (x.z != 0.f) | (x.w != 0.f);
    }
    if (__ballot(any) != 0ull && lane == 0) sWee = 1;
  }
  __syncthreads();   // one-time: full drain is fine here
  const int wee = sWee;

  // ---- per-thread state ----
  float vE = -65.f, ge = 0.f, gi = 0.f; int rE = 0;   // E neuron = tid
  float vI = -65.f, gI = 0.f; int rI = 0;             // I neuron = lane (replicated/wave)
  float vO = -65.f, gO = 0.f, accO = 0.f; int rO = 0; // output (wave 0, lanes<10)

  unsigned long long mE = 0ull;   // prev-step E mask, own word (SGPR)
  unsigned long long mI = 0ull;   // prev-step I mask (SGPR, replicated)

  int par = 0;
  // input pipeline: cur = in[t], n1 = in[t+1] (2-step prefetch depth)
  float cur = g_in[b * N_IN + lane];
  float n1  = g_in[((T > 1 ? 1 : 0) * BB + b) * N_IN + lane];

  for (int t = 0; t < T; ++t) {
    const int t2 = (t + 2 < T) ? (t + 2) : (T - 1);
    float n2 = g_in[(t2 * BB + b) * N_IN + lane];   // prefetch t+2 (2 steps of slack)

    const unsigned long long mIn = __ballot(cur != 0.f);

    // ---- issue W0 global loads for current input spikes (consume after LDS loop) ----
    unsigned long long aRem;
    bool va[4]; int ja[4]; float fa[4];
    {
      unsigned long long a = mIn;
#pragma unroll
      for (int k = 0; k < 4; ++k) {
        va[k] = (a != 0ull); ja[k] = va[k] ? (__ffsll(a) - 1) : 0; a &= (a - 1ull);
      }
      aRem = a;   // leftover (>4 input spikes — rare)
#pragma unroll
      for (int k = 0; k < 4; ++k) fa[k] = g_W0[ja[k] * N_E + tid];   // raw; clamp at use
    }

    // ---- LDS gathers over PREVIOUS masks: kie (I->E, col=tid), pEI (E->I word, col=lane) ----
    float kie = 0.f, pEI = 0.f;
    {
      unsigned long long c = mI, e = mE;
      while (c | e) {
        int jc[8]; bool vc[8];
#pragma unroll
        for (int k = 0; k < 8; ++k) {
          vc[k] = (c != 0ull); jc[k] = vc[k] ? (__ffsll(c) - 1) : 0; c &= (c - 1ull);
        }
        int je[8]; bool ve[8];
#pragma unroll
        for (int k = 0; k < 8; ++k) {
          ve[k] = (e != 0ull); je[k] = ve[k] ? (__ffsll(e) - 1) : 0; e &= (e - 1ull);
        }
        float fc[8], fe[8];
#pragma unroll
        for (int k = 0; k < 8; ++k) {
          fc[k] = sWie[jc[k] * N_E + tid];
          fe[k] = sWei[(wav * 64 + je[k]) * N_I + lane];
        }
#pragma unroll
        for (int k = 0; k < 8; ++k) kie += vc[k] ? fc[k] : 0.f;
#pragma unroll
        for (int k = 0; k < 8; ++k) pEI += ve[k] ? fe[k] : 0.f;
      }
    }

    // ---- consume W0 loads (vmcnt wait overlapped with the LDS loop above) ----
    float kin = 0.f;
#pragma unroll
    for (int k = 0; k < 4; ++k) kin += va[k] ? fmaxf(fa[k], 0.f) : 0.f;
    while (aRem) {   // rare: >4 input spikes this step (ascending order continues)
      int j = __ffsll(aRem) - 1; aRem &= (aRem - 1ull);
      kin += fmaxf(g_W0[j * N_E + tid], 0.f);
    }

    // ---- E<-E recurrent fallback (dead for this data) ----
    float kee = 0.f;
    if (wee) {
      unsigned long long m0 = sME[par][0], m1 = sME[par][1];
      unsigned long long m2 = sME[par][2], m3 = sME[par][3];
      while (m0 | m1 | m2 | m3) {
        bool v[4]; int j[4];
#pragma unroll
        for (int k = 0; k < 4; ++k) {
          bool h0 = (m0 != 0ull), h1 = (m1 != 0ull), h2 = (m2 != 0ull), h3 = (m3 != 0ull);
          int idx = 0;
          if (h0)      { idx = __ffsll(m0) - 1;       m0 &= (m0 - 1ull); }
          else if (h1) { idx = 64 + __ffsll(m1) - 1;  m1 &= (m1 - 1ull); }
          else if (h2) { idx = 128 + __ffsll(m2) - 1; m2 &= (m2 - 1ull); }
          else if (h3) { idx = 192 + __ffsll(m3) - 1; m3 &= (m3 - 1ull); }
          v[k] = h0 | h1 | h2 | h3; j[k] = idx;
        }
        float f[4];
#pragma unroll
        for (int k = 0; k < 4; ++k) f[k] = g_Wee[j[k] * N_E + tid];
#pragma unroll
        for (int k = 0; k < 4; ++k) kee += v[k] ? f[k] : 0.f;
      }
    }

    // ---- E LIF (COBA, C_m=1, g_L=0.05, ref=12) ----
    ge = ((ge + kin) + kee) * dA;
    gi = (gi + kie) * dG;
    {
      float t2f = ge * (0.f - vE);
      float t3f = gi * (-80.f - vE);
      float Itot = t2f + t3f;
      float dv = 0.25f * ((-0.05f) * (vE - (-65.f)) + Itot);
      dv = dv * 0.0125f + dv * 0.9875f;      // _scale_grad forward (not fp-identity)
      vE = fmaxf(vE + dv, -200.f);
      rE = rE - 1; if (rE < 0) rE = 0;
      bool can = (rE == 0);
      bool sE = ((vE - (-50.f)) >= 0.f) && can;
      vE = (sE || !can) ? -65.f : vE;
      rE = sE ? 12 : rE;
      unsigned long long fresh = __ballot(sE);
      if (lane == 0) sME[par ^ 1][wav] = fresh;   // only consumed by wee path

      // ---- E->O word partial over FRESH own-word mask (LDS W1) ----
      float ko = 0.f;
      {
        unsigned long long m = fresh;
        while (m) {
          int j[8]; bool v[8];
#pragma unroll
          for (int k = 0; k < 8; ++k) {
            v[k] = (m != 0ull); j[k] = v[k] ? (__ffsll(m) - 1) : 0; m &= (m - 1ull);
          }
          float f[8];
#pragma unroll
          for (int k = 0; k < 8; ++k) f[k] = sW1[(wav * 64 + j[k]) * N_OUT + col];
#pragma unroll
          for (int k = 0; k < 8; ++k) ko += v[k] ? f[k] : 0.f;
        }
      }
      sP[par][wav][lane] = pEI;
      if (lane < N_OUT) sKo[par][wav][lane] = ko;
      mE = fresh;
    }

    wg_barrier_lds();   // the ONLY barrier per step — LDS-drain only, vmcnt flies

    // ---- phase B: I LIF replicated on every wave (identical fp -> same ballot) ----
    {
      float p = ((sP[par][0][lane] + sP[par][1][lane]) + sP[par][2][lane]) + sP[par][3][lane];
      gI = (gI + p) * dA;
      float Ii = gI * (0.f - vI);
      float dvi = 0.5f * ((-0.1f) * (vI - (-65.f)) + Ii);
      dvi = dvi * 0.0125f + dvi * 0.9875f;
      vI = fmaxf(vI + dvi, -200.f);
      rI = rI - 1; if (rI < 0) rI = 0;
      bool canI = (rI == 0);
      bool sI = ((vI - (-50.f)) >= 0.f) && canI;
      vI = (sI || !canI) ? -65.f : vI;
      rI = sI ? 6 : rI;
      mI = __ballot(sI);
    }

    // ---- output LIF (wave 0 only; runs in other waves' next-phase-A slack) ----
    if (wav == 0 && lane < N_OUT) {
      float k4 = ((sKo[par][0][lane] + sKo[par][1][lane]) + sKo[par][2][lane]) + sKo[par][3][lane];
      gO = (gO + k4) * dA;
      float Io = gO * (0.f - vO);
      float dvo = 0.25f * ((-0.05f) * (vO - (-65.f)) + Io);
      dvo = dvo * 0.0125f + dvo * 0.9875f;
      vO = fmaxf(vO + dvo, -200.f);
      rO = rO - 1; if (rO < 0) rO = 0;
      bool canO = (rO == 0);
      bool sO = ((vO - (-50.f)) >= 0.f) && canO;
      vO = (sO || !canO) ? -65.f : vO;
      rO = sO ? 12 : rO;
      accO += sO ? 1.f : 0.f;
    }

    par ^= 1;
    cur = n1;
    n1 = n2;
  }

  if (wav == 0 && lane < N_OUT) g_out[b * N_OUT + lane] = accO;
}

extern "C" void kernel_launch(void* const* d_in, const int* in_sizes, int n_in,
                              void* d_out, int out_size, void* d_ws, size_t ws_size,
                              hipStream_t stream) {
  const float* g_in  = (const float*)d_in[0];
  const float* g_W0  = (const float*)d_in[1];
  const float* g_W1  = (const float*)d_in[2];
  const float* g_Wee = (const float*)d_in[3];
  const float* g_Wei = (const float*)d_in[4];
  const float* g_Wie = (const float*)d_in[5];
  float* out = (float*)d_out;
  int T = in_sizes[0] / (BB * N_IN);
  float dA = (float)exp(-0.25 / 2.0);   // tau_ampa = 2.0
  float dG = (float)exp(-0.25 / 9.0);   // tau_gaba = 9.0
  ping_kernel<<<dim3(BB), dim3(256), 0, stream>>>(g_in, g_W0, g_W1, g_Wee, g_Wei, g_Wie, out, T, dA, dG);
}